// Round 5
// baseline (4154.568 us; speedup 1.0000x reference)
//
#include <hip/hip_runtime.h>

#define D_IN 512
#define D_H 1024
#define D_OUT 32000
#define NB 64
#define NS 512

typedef __attribute__((ext_vector_type(8))) short short8;
typedef __attribute__((ext_vector_type(8))) __bf16 bf16x8;
typedef __attribute__((ext_vector_type(4))) float f32x4;

__device__ __forceinline__ unsigned short f2bf(float f) {
  unsigned int u = __float_as_uint(f);
  u += 0x7fffu + ((u >> 16) & 1u);
  return (unsigned short)(u >> 16);
}
__device__ __forceinline__ float bf2f(unsigned short s) {
  return __uint_as_float(((unsigned int)s) << 16);
}

__device__ __forceinline__ f32x4 mfma_bf16(short8 a, short8 b, f32x4 c) {
  return __builtin_amdgcn_mfma_f32_16x16x32_bf16(
      __builtin_bit_cast(bf16x8, a), __builtin_bit_cast(bf16x8, b), c, 0, 0, 0);
}

// ---------------------------------------------------------------------------
// h exchange: tagged u64 quanta. hx[group(4)][buf(2)][b(16)][k2(512)]:
//   u64 = hi_pair (bf16 h[2k],h[2k+1]) | lo_pair<<32, where each lo bf16's
//   LSB carries the step tag bit ((t>>1)&1). Data is its own ready flag:
//   no producer drain, no separate flag store -> 2 LLC trips per step.
// init writes h0 (tag 0) to buf0 and tag=1 poison to buf1 (0xAA-poison from
// the harness has tag bits 0, which would alias t=1's tag — poison avoids it).
// ---------------------------------------------------------------------------
__global__ __launch_bounds__(256) void rnn_init(const float* __restrict__ h0,
                                                unsigned long long* __restrict__ hx) {
  int idx = blockIdx.x * 256 + threadIdx.x;  // 0..32767 (pairs)
  int bg = idx >> 9;                         // batch 0..63
  int k2 = idx & 511;
  int g = bg >> 4, bl = bg & 15;
  float v0 = h0[bg * 1024 + k2 * 2];
  float v1 = h0[bg * 1024 + k2 * 2 + 1];
  unsigned int h0h = f2bf(v0), h1h = f2bf(v1);
  unsigned int l0 = (unsigned int)f2bf(v0 - bf2f((unsigned short)h0h)) & ~1u;  // tag 0
  unsigned int l1 = (unsigned int)f2bf(v1 - bf2f((unsigned short)h1h)) & ~1u;
  unsigned long long real =
      (unsigned long long)(h0h | (h1h << 16)) |
      ((unsigned long long)(l0 | (l1 << 16)) << 32);
  hx[((size_t)(g * 2 + 0) * 16 + bl) * 512 + k2] = real;
  hx[((size_t)(g * 2 + 1) * 16 + bl) * 512 + k2] = 0x0001000100000000ull;  // tag=1 poison
}

// ---------------------------------------------------------------------------
// pack W_ih [512][1024] fp32 -> B-fragment layout, hi/lo bf16 planes
// ---------------------------------------------------------------------------
__global__ __launch_bounds__(256) void rnn_pack_wih(const float* __restrict__ W_ih,
                                                    unsigned short* __restrict__ bhi,
                                                    unsigned short* __restrict__ blo) {
  int idx = blockIdx.x * 256 + threadIdx.x;  // 0..524287
  int j = idx & 7;
  int l = (idx >> 3) & 63;
  int kc = (idx >> 9) & 15;
  int nc = idx >> 13;
  int k = kc * 32 + ((l >> 4) << 3) + j;
  int n = nc * 16 + (l & 15);
  float v = W_ih[(size_t)k * D_H + n];
  unsigned short h = f2bf(v);
  bhi[idx] = h;
  blo[idx] = f2bf(v - bf2f(h));
}

// ---------------------------------------------------------------------------
// stage 1: xw[t*64+b][n] = embed[tokens[b][t]] @ W_ih + bias_hh   (bf16x3 MFMA)
// ---------------------------------------------------------------------------
__global__ __launch_bounds__(256) void rnn_stage1(const int* __restrict__ tokens,
                                                  const float* __restrict__ embed,
                                                  const unsigned short* __restrict__ bhi,
                                                  const unsigned short* __restrict__ blo,
                                                  const float* __restrict__ bias,
                                                  float* __restrict__ xw) {
  int bx = blockIdx.x;
  int mt = bx >> 4, nt = bx & 15;
  int tid = threadIdx.x;
  int w = tid >> 6, l = tid & 63;
  int q = l >> 4;

  int m = mt * 64 + w * 16 + (l & 15);  // A-operand row
  int b = m & 63, t = m >> 6;
  int tok = tokens[b * NS + t];
  const float* arow = embed + (size_t)tok * D_IN;

  f32x4 acc[4];
#pragma unroll
  for (int i = 0; i < 4; ++i) acc[i] = (f32x4){0.f, 0.f, 0.f, 0.f};

  for (int c = 0; c < 16; ++c) {
    const float* ap = arow + c * 32 + q * 8;
    float4 f0 = *(const float4*)ap;
    float4 f1 = *(const float4*)(ap + 4);
    float fa[8] = {f0.x, f0.y, f0.z, f0.w, f1.x, f1.y, f1.z, f1.w};
    short8 ahi, alo;
#pragma unroll
    for (int j = 0; j < 8; ++j) {
      unsigned short hh = f2bf(fa[j]);
      ahi[j] = (short)hh;
      alo[j] = (short)f2bf(fa[j] - bf2f(hh));
    }
#pragma unroll
    for (int ni = 0; ni < 4; ++ni) {
      int ncg = nt * 4 + ni;
      size_t boff = ((size_t)(ncg * 16 + c) * 64 + l) * 8;
      short8 bh = *(const short8*)(bhi + boff);
      short8 bl_ = *(const short8*)(blo + boff);
      acc[ni] = mfma_bf16(ahi, bh, acc[ni]);
      acc[ni] = mfma_bf16(alo, bh, acc[ni]);
      acc[ni] = mfma_bf16(ahi, bl_, acc[ni]);
    }
  }

#pragma unroll
  for (int ni = 0; ni < 4; ++ni) {
    int col = nt * 64 + ni * 16 + (l & 15);
    float bv = bias[col];
#pragma unroll
    for (int r = 0; r < 4; ++r) {
      int row = mt * 64 + w * 16 + q * 4 + r;  // D-layout row
      xw[(size_t)row * D_H + col] = acc[ni][r] + bv;
    }
  }
}

// ---------------------------------------------------------------------------
// stage 2: persistent recurrence. 128 WGs = 4 batch-groups x 32 j-tiles.
// W_hh slice (1024 x 32) resident in LDS (bf16 hi/lo, B-fragment order).
// Sync: data-as-flag tagged u64 exchange (see rnn_init comment). Each wave
// speculatively loads its 32 u64 inputs, validates tags, retries if stale.
// One barrier per step (red[] ping-pong).
// ---------------------------------------------------------------------------
__global__ __launch_bounds__(256, 1) void rnn_recur(const float* __restrict__ xw,
                                                    const float* __restrict__ W_hh,
                                                    unsigned long long* __restrict__ hx,
                                                    float* __restrict__ h_last) {
  __shared__ short Whi[32768];          // 64 KB
  __shared__ short Wlo[32768];          // 64 KB
  __shared__ float red[2][4][16][33];   // 16896 B (total 147968 -> 1 WG/CU)

  const int tid = threadIdx.x;
  const int bx = blockIdx.x;
  const int g = bx >> 5;     // batch group 0..3
  const int jt = bx & 31;    // j tile 0..31
  const int jcol0 = jt * 32;
  const int w = tid >> 6;
  const int l = tid & 63;
  const int q = l >> 4;
  const int b_lane = l & 15;

  // one-time: load + split W_hh slice into LDS in B-fragment order.
  for (int v = tid; v < 32768; v += 256) {
    int j = v & 7;
    int ll = (v >> 3) & 63;
    int c = (v >> 9) & 31;
    int s = v >> 14;
    int k = c * 32 + ((ll >> 4) << 3) + j;
    int n = s * 16 + (ll & 15);
    float wv = W_hh[(size_t)k * D_H + jcol0 + n];
    unsigned short hh = f2bf(wv);
    Whi[v] = (short)hh;
    Wlo[v] = (short)f2bf(wv - bf2f(hh));
  }
  __syncthreads();

  // epilogue constants: 2 adjacent j per thread
  const int be = tid >> 4;            // batch 0..15
  const int je2 = (tid & 15) * 2;     // j 0,2,..,30
  const int brow = g * 16 + be;

  for (int t = 1; t <= NS; ++t) {
    const int rbuf = (t - 1) & 1;
    const int wbuf = t & 1;
    const unsigned int etagp = (((t - 1) >> 1) & 1) ? 0x00010001u : 0u;
    const unsigned int wtag = (unsigned int)((t >> 1) & 1);

    // prefetch this step's xw pair (hides under the sweep)
    const float* xwp = xw + ((size_t)(t - 1) * 64 + brow) * D_H + jcol0 + je2;
    float xv0 = xwp[0];
    float xv1 = xwp[1];

    // ---- speculative sweep + tag validation (per wave, no flags) ----
    const unsigned long long* hp =
        hx + ((size_t)(g * 2 + rbuf) * 16 + b_lane) * 512;
    unsigned long long hb[32];
    while (1) {
#pragma unroll
      for (int i = 0; i < 8; ++i) {
        int u0 = (w * 8 + i) * 16 + q * 4;
#pragma unroll
        for (int j = 0; j < 4; ++j)
          hb[i * 4 + j] = __hip_atomic_load(hp + u0 + j, __ATOMIC_RELAXED,
                                            __HIP_MEMORY_SCOPE_AGENT);
      }
      unsigned int bad = 0;
#pragma unroll
      for (int m = 0; m < 32; ++m)
        bad |= ((unsigned int)(hb[m] >> 32) ^ etagp) & 0x00010001u;
      if (__all(bad == 0)) break;
      __builtin_amdgcn_s_sleep(1);
    }

    // ---- MFMA chains, both 16-col subtiles ----
    f32x4 a00 = {0.f, 0.f, 0.f, 0.f}, a01 = a00, a02 = a00;
    f32x4 a10 = a00, a11 = a00, a12 = a00;
#pragma unroll
    for (int i = 0; i < 8; ++i) {
      int c = w * 8 + i;
      uint4 ah = {(unsigned int)hb[i * 4 + 0], (unsigned int)hb[i * 4 + 1],
                  (unsigned int)hb[i * 4 + 2], (unsigned int)hb[i * 4 + 3]};
      uint4 al = {(unsigned int)(hb[i * 4 + 0] >> 32),
                  (unsigned int)(hb[i * 4 + 1] >> 32),
                  (unsigned int)(hb[i * 4 + 2] >> 32),
                  (unsigned int)(hb[i * 4 + 3] >> 32)};
      short8 as = __builtin_bit_cast(short8, ah);
      short8 ls = __builtin_bit_cast(short8, al);
      short8 bh0 = *(const short8*)(Whi + c * 512 + l * 8);
      short8 bl0 = *(const short8*)(Wlo + c * 512 + l * 8);
      short8 bh1 = *(const short8*)(Whi + 16384 + c * 512 + l * 8);
      short8 bl1 = *(const short8*)(Wlo + 16384 + c * 512 + l * 8);
      a00 = mfma_bf16(as, bh0, a00);
      a01 = mfma_bf16(ls, bh0, a01);
      a02 = mfma_bf16(as, bl0, a02);
      a10 = mfma_bf16(as, bh1, a10);
      a11 = mfma_bf16(ls, bh1, a11);
      a12 = mfma_bf16(as, bl1, a12);
    }
    f32x4 s0 = a00 + a01 + a02;
    f32x4 s1 = a10 + a11 + a12;
#pragma unroll
    for (int r = 0; r < 4; ++r) {
      red[rbuf][w][q * 4 + r][b_lane] = s0[r];
      red[rbuf][w][q * 4 + r][16 + b_lane] = s1[r];
    }
    __syncthreads();  // the ONLY barrier per step (red ping-pong covers reuse)

    // ---- epilogue: every thread handles (be, je2) and (be, je2+1) ----
    float z0 = red[rbuf][0][be][je2] + red[rbuf][1][be][je2] +
               red[rbuf][2][be][je2] + red[rbuf][3][be][je2] + xv0;
    float z1 = red[rbuf][0][be][je2 + 1] + red[rbuf][1][be][je2 + 1] +
               red[rbuf][2][be][je2 + 1] + red[rbuf][3][be][je2 + 1] + xv1;
    float hv0 = tanhf(z0);
    float hv1 = tanhf(z1);
    unsigned int h0h = f2bf(hv0), h1h = f2bf(hv1);
    unsigned int l0 = ((unsigned int)f2bf(hv0 - bf2f((unsigned short)h0h)) & ~1u) | wtag;
    unsigned int l1 = ((unsigned int)f2bf(hv1 - bf2f((unsigned short)h1h)) & ~1u) | wtag;
    unsigned long long val =
        (unsigned long long)(h0h | (h1h << 16)) |
        ((unsigned long long)(l0 | (l1 << 16)) << 32);
    unsigned long long* dst =
        hx + ((size_t)(g * 2 + wbuf) * 16 + be) * 512 + ((jcol0 + je2) >> 1);
    __hip_atomic_store(dst, val, __ATOMIC_RELAXED, __HIP_MEMORY_SCOPE_AGENT);
    if (t == NS) {
      h_last[(size_t)brow * 1024 + jcol0 + je2] = hv0;
      h_last[(size_t)brow * 1024 + jcol0 + je2 + 1] = hv1;
    }
  }
}

// ---------------------------------------------------------------------------
// stage 3: y[b][j] = h_last[b][:] . W_out[:][j] + b_out[j]   (fp32 vector)
// ---------------------------------------------------------------------------
__global__ __launch_bounds__(256, 2) void rnn_out(const float* __restrict__ h_last,
                                                  const float* __restrict__ W_out,
                                                  const float* __restrict__ b_out,
                                                  float* __restrict__ out) {
  __shared__ float smem[16384];
  int tid = threadIdx.x;
  int jl = tid & 127;
  int kh = tid >> 7;
  int j = blockIdx.x * 128 + jl;

  float acc[64];
#pragma unroll
  for (int b = 0; b < 64; ++b) acc[b] = 0.f;

  for (int kc = 0; kc < 4; ++kc) {
    __syncthreads();
    for (int v = tid; v < 16384; v += 256) {
      int kh2 = v >> 13;
      int b = (v >> 7) & 63;
      int kk = v & 127;
      smem[v] = h_last[(size_t)b * 1024 + kh2 * 512 + kc * 128 + kk];
    }
    __syncthreads();
    int kbase = kh * 512 + kc * 128;
    for (int kkc = 0; kkc < 16; ++kkc) {
      float wreg[8];
#pragma unroll
      for (int i = 0; i < 8; ++i)
        wreg[i] = W_out[(size_t)(kbase + kkc * 8 + i) * D_OUT + j];
#pragma unroll
      for (int b = 0; b < 64; ++b) {
        const float* hp = &smem[kh * 8192 + b * 128 + kkc * 8];
#pragma unroll
        for (int i = 0; i < 8; ++i) acc[b] += hp[i] * wreg[i];
      }
    }
  }
  __syncthreads();
  if (kh == 1) {
#pragma unroll
    for (int b = 0; b < 64; ++b) smem[jl * 65 + b] = acc[b];
  }
  __syncthreads();
  if (kh == 0) {
    float bo = b_out[j];
#pragma unroll
    for (int b = 0; b < 64; ++b)
      out[(size_t)b * D_OUT + j] = acc[b] + smem[jl * 65 + b] + bo;
  }
}

// ---------------------------------------------------------------------------
extern "C" void kernel_launch(void* const* d_in, const int* in_sizes, int n_in,
                              void* d_out, int out_size, void* d_ws, size_t ws_size,
                              hipStream_t stream) {
  const int* tokens = (const int*)d_in[0];
  const float* h0 = (const float*)d_in[1];
  const float* embed = (const float*)d_in[2];
  const float* W_ih = (const float*)d_in[3];
  const float* W_hh = (const float*)d_in[4];
  const float* bias_hh = (const float*)d_in[5];
  const float* W_out = (const float*)d_in[6];
  const float* b_out = (const float*)d_in[7];
  float* out = (float*)d_out;

  char* ws = (char*)d_ws;
  // workspace layout (bytes)
  float* xw = (float*)(ws);                                    // 134217728
  unsigned short* wih_hi = (unsigned short*)(ws + 134217728);  // 1048576
  unsigned short* wih_lo = (unsigned short*)(ws + 135266304);  // 1048576
  unsigned long long* hx = (unsigned long long*)(ws + 136314880);  // 524288
  float* h_last = (float*)(ws + 136839168);                    // 262144
  // total: 137101312 bytes

  rnn_init<<<128, 256, 0, stream>>>(h0, hx);
  rnn_pack_wih<<<2048, 256, 0, stream>>>(W_ih, wih_hi, wih_lo);
  rnn_stage1<<<8192, 256, 0, stream>>>(tokens, embed, wih_hi, wih_lo, bias_hh, xw);
  rnn_recur<<<128, 256, 0, stream>>>(xw, W_hh, hx, h_last);
  rnn_out<<<250, 256, 0, stream>>>(h_last, W_out, b_out, out);
}

// Round 6
// 3837.110 us; speedup vs baseline: 1.0827x; 1.0827x over previous
//
#include <hip/hip_runtime.h>

#define D_IN 512
#define D_H 1024
#define D_OUT 32000
#define NB 64
#define NS 512

typedef __attribute__((ext_vector_type(8))) short short8;
typedef __attribute__((ext_vector_type(8))) __bf16 bf16x8;
typedef __attribute__((ext_vector_type(4))) float f32x4;

__device__ __forceinline__ unsigned short f2bf(float f) {
  unsigned int u = __float_as_uint(f);
  u += 0x7fffu + ((u >> 16) & 1u);
  return (unsigned short)(u >> 16);
}
__device__ __forceinline__ float bf2f(unsigned short s) {
  return __uint_as_float(((unsigned int)s) << 16);
}

__device__ __forceinline__ f32x4 mfma_bf16(short8 a, short8 b, f32x4 c) {
  return __builtin_amdgcn_mfma_f32_16x16x32_bf16(
      __builtin_bit_cast(bf16x8, a), __builtin_bit_cast(bf16x8, b), c, 0, 0, 0);
}

// ---------------------------------------------------------------------------
// h exchange: tagged u64 quanta. hx[group(4)][buf(2)][b(16)][k2(512)]:
//   u64 = hi_pair (bf16 h[2k],h[2k+1]) | lo_pair<<32, where each lo bf16's
//   LSB carries the step tag bit ((t>>1)&1). Data is its own ready flag:
//   no producer drain, no separate flag store -> 2 LLC trips per step.
// init writes h0 (tag 0) to buf0 and tag=1 poison to buf1 (0xAA-poison from
// the harness has tag bits 0, which would alias t=1's tag — poison avoids it).
// ---------------------------------------------------------------------------
__global__ __launch_bounds__(256) void rnn_init(const float* __restrict__ h0,
                                                unsigned long long* __restrict__ hx) {
  int idx = blockIdx.x * 256 + threadIdx.x;  // 0..32767 (pairs)
  int bg = idx >> 9;                         // batch 0..63
  int k2 = idx & 511;
  int g = bg >> 4, bl = bg & 15;
  float v0 = h0[bg * 1024 + k2 * 2];
  float v1 = h0[bg * 1024 + k2 * 2 + 1];
  unsigned int h0h = f2bf(v0), h1h = f2bf(v1);
  unsigned int l0 = (unsigned int)f2bf(v0 - bf2f((unsigned short)h0h)) & ~1u;  // tag 0
  unsigned int l1 = (unsigned int)f2bf(v1 - bf2f((unsigned short)h1h)) & ~1u;
  unsigned long long real =
      (unsigned long long)(h0h | (h1h << 16)) |
      ((unsigned long long)(l0 | (l1 << 16)) << 32);
  hx[((size_t)(g * 2 + 0) * 16 + bl) * 512 + k2] = real;
  hx[((size_t)(g * 2 + 1) * 16 + bl) * 512 + k2] = 0x0001000100000000ull;  // tag=1 poison
}

// ---------------------------------------------------------------------------
// pack W_ih [512][1024] fp32 -> B-fragment layout, hi/lo bf16 planes
// ---------------------------------------------------------------------------
__global__ __launch_bounds__(256) void rnn_pack_wih(const float* __restrict__ W_ih,
                                                    unsigned short* __restrict__ bhi,
                                                    unsigned short* __restrict__ blo) {
  int idx = blockIdx.x * 256 + threadIdx.x;  // 0..524287
  int j = idx & 7;
  int l = (idx >> 3) & 63;
  int kc = (idx >> 9) & 15;
  int nc = idx >> 13;
  int k = kc * 32 + ((l >> 4) << 3) + j;
  int n = nc * 16 + (l & 15);
  float v = W_ih[(size_t)k * D_H + n];
  unsigned short h = f2bf(v);
  bhi[idx] = h;
  blo[idx] = f2bf(v - bf2f(h));
}

// ---------------------------------------------------------------------------
// stage 1: xw[t*64+b][n] = embed[tokens[b][t]] @ W_ih + bias_hh   (bf16x3 MFMA)
// ---------------------------------------------------------------------------
__global__ __launch_bounds__(256) void rnn_stage1(const int* __restrict__ tokens,
                                                  const float* __restrict__ embed,
                                                  const unsigned short* __restrict__ bhi,
                                                  const unsigned short* __restrict__ blo,
                                                  const float* __restrict__ bias,
                                                  float* __restrict__ xw) {
  int bx = blockIdx.x;
  int mt = bx >> 4, nt = bx & 15;
  int tid = threadIdx.x;
  int w = tid >> 6, l = tid & 63;
  int q = l >> 4;

  int m = mt * 64 + w * 16 + (l & 15);  // A-operand row
  int b = m & 63, t = m >> 6;
  int tok = tokens[b * NS + t];
  const float* arow = embed + (size_t)tok * D_IN;

  f32x4 acc[4];
#pragma unroll
  for (int i = 0; i < 4; ++i) acc[i] = (f32x4){0.f, 0.f, 0.f, 0.f};

  for (int c = 0; c < 16; ++c) {
    const float* ap = arow + c * 32 + q * 8;
    float4 f0 = *(const float4*)ap;
    float4 f1 = *(const float4*)(ap + 4);
    float fa[8] = {f0.x, f0.y, f0.z, f0.w, f1.x, f1.y, f1.z, f1.w};
    short8 ahi, alo;
#pragma unroll
    for (int j = 0; j < 8; ++j) {
      unsigned short hh = f2bf(fa[j]);
      ahi[j] = (short)hh;
      alo[j] = (short)f2bf(fa[j] - bf2f(hh));
    }
#pragma unroll
    for (int ni = 0; ni < 4; ++ni) {
      int ncg = nt * 4 + ni;
      size_t boff = ((size_t)(ncg * 16 + c) * 64 + l) * 8;
      short8 bh = *(const short8*)(bhi + boff);
      short8 bl_ = *(const short8*)(blo + boff);
      acc[ni] = mfma_bf16(ahi, bh, acc[ni]);
      acc[ni] = mfma_bf16(alo, bh, acc[ni]);
      acc[ni] = mfma_bf16(ahi, bl_, acc[ni]);
    }
  }

#pragma unroll
  for (int ni = 0; ni < 4; ++ni) {
    int col = nt * 64 + ni * 16 + (l & 15);
    float bv = bias[col];
#pragma unroll
    for (int r = 0; r < 4; ++r) {
      int row = mt * 64 + w * 16 + q * 4 + r;  // D-layout row
      xw[(size_t)row * D_H + col] = acc[ni][r] + bv;
    }
  }
}

// ---------------------------------------------------------------------------
// stage 2: persistent recurrence. 128 WGs = 4 batch-groups x 32 j-tiles.
// W_hh slice (1024 x 32) resident in LDS (bf16 hi/lo, B-fragment order).
// Sync: data-as-flag tagged u64 exchange. Initial sweep loads all 32 u64s
// once (the unavoidable h broadcast); retries re-load ONLY stale elements
// (exec-masked) so spin traffic is ~zero — R5's full-resweep clogged the
// fabric at ~19 TB/s and throttled the producers (the R5 regression).
// ---------------------------------------------------------------------------
__global__ __launch_bounds__(256, 1) void rnn_recur(const float* __restrict__ xw,
                                                    const float* __restrict__ W_hh,
                                                    unsigned long long* __restrict__ hx,
                                                    float* __restrict__ h_last) {
  __shared__ short Whi[32768];          // 64 KB
  __shared__ short Wlo[32768];          // 64 KB
  __shared__ float red[2][4][16][33];   // 16896 B (total 147968 -> 1 WG/CU)

  const int tid = threadIdx.x;
  const int bx = blockIdx.x;
  const int g = bx >> 5;     // batch group 0..3
  const int jt = bx & 31;    // j tile 0..31
  const int jcol0 = jt * 32;
  const int w = tid >> 6;
  const int l = tid & 63;
  const int q = l >> 4;
  const int b_lane = l & 15;

  // one-time: load + split W_hh slice into LDS in B-fragment order.
  for (int v = tid; v < 32768; v += 256) {
    int j = v & 7;
    int ll = (v >> 3) & 63;
    int c = (v >> 9) & 31;
    int s = v >> 14;
    int k = c * 32 + ((ll >> 4) << 3) + j;
    int n = s * 16 + (ll & 15);
    float wv = W_hh[(size_t)k * D_H + jcol0 + n];
    unsigned short hh = f2bf(wv);
    Whi[v] = (short)hh;
    Wlo[v] = (short)f2bf(wv - bf2f(hh));
  }
  __syncthreads();

  // epilogue constants: 2 adjacent j per thread
  const int be = tid >> 4;            // batch 0..15
  const int je2 = (tid & 15) * 2;     // j 0,2,..,30
  const int brow = g * 16 + be;

  for (int t = 1; t <= NS; ++t) {
    const int rbuf = (t - 1) & 1;
    const int wbuf = t & 1;
    const unsigned int etagp = (((t - 1) >> 1) & 1) ? 0x00010001u : 0u;
    const unsigned int wtag = (unsigned int)((t >> 1) & 1);

    // prefetch this step's xw pair (hides under the sweep)
    const float* xwp = xw + ((size_t)(t - 1) * 64 + brow) * D_H + jcol0 + je2;
    float xv0 = xwp[0];
    float xv1 = xwp[1];

    // ---- initial sweep: all 32 u64s, one pipelined LLC round ----
    const unsigned long long* hp =
        hx + ((size_t)(g * 2 + rbuf) * 16 + b_lane) * 512;
    unsigned long long hb[32];
#pragma unroll
    for (int i = 0; i < 8; ++i) {
      int u0 = (w * 8 + i) * 16 + q * 4;
#pragma unroll
      for (int j = 0; j < 4; ++j)
        hb[i * 4 + j] = __hip_atomic_load(hp + u0 + j, __ATOMIC_RELAXED,
                                          __HIP_MEMORY_SCOPE_AGENT);
    }
    // ---- targeted retry: re-load ONLY stale elements ----
    while (1) {
      unsigned int bad = 0;
#pragma unroll
      for (int m = 0; m < 32; ++m)
        bad |= ((unsigned int)(hb[m] >> 32) ^ etagp) & 0x00010001u;
      if (__all(bad == 0)) break;
      __builtin_amdgcn_s_sleep(1);
#pragma unroll
      for (int i = 0; i < 8; ++i) {
#pragma unroll
        for (int j = 0; j < 4; ++j) {
          int m = i * 4 + j;
          if ((((unsigned int)(hb[m] >> 32) ^ etagp) & 0x00010001u) != 0u) {
            int u0 = (w * 8 + i) * 16 + q * 4;
            hb[m] = __hip_atomic_load(hp + u0 + j, __ATOMIC_RELAXED,
                                      __HIP_MEMORY_SCOPE_AGENT);
          }
        }
      }
    }

    // ---- MFMA chains, both 16-col subtiles ----
    f32x4 a00 = {0.f, 0.f, 0.f, 0.f}, a01 = a00, a02 = a00;
    f32x4 a10 = a00, a11 = a00, a12 = a00;
#pragma unroll
    for (int i = 0; i < 8; ++i) {
      int c = w * 8 + i;
      uint4 ah = {(unsigned int)hb[i * 4 + 0], (unsigned int)hb[i * 4 + 1],
                  (unsigned int)hb[i * 4 + 2], (unsigned int)hb[i * 4 + 3]};
      uint4 al = {(unsigned int)(hb[i * 4 + 0] >> 32),
                  (unsigned int)(hb[i * 4 + 1] >> 32),
                  (unsigned int)(hb[i * 4 + 2] >> 32),
                  (unsigned int)(hb[i * 4 + 3] >> 32)};
      short8 as = __builtin_bit_cast(short8, ah);
      short8 ls = __builtin_bit_cast(short8, al);
      short8 bh0 = *(const short8*)(Whi + c * 512 + l * 8);
      short8 bl0 = *(const short8*)(Wlo + c * 512 + l * 8);
      short8 bh1 = *(const short8*)(Whi + 16384 + c * 512 + l * 8);
      short8 bl1 = *(const short8*)(Wlo + 16384 + c * 512 + l * 8);
      a00 = mfma_bf16(as, bh0, a00);
      a01 = mfma_bf16(ls, bh0, a01);
      a02 = mfma_bf16(as, bl0, a02);
      a10 = mfma_bf16(as, bh1, a10);
      a11 = mfma_bf16(ls, bh1, a11);
      a12 = mfma_bf16(as, bl1, a12);
    }
    f32x4 s0 = a00 + a01 + a02;
    f32x4 s1 = a10 + a11 + a12;
#pragma unroll
    for (int r = 0; r < 4; ++r) {
      red[rbuf][w][q * 4 + r][b_lane] = s0[r];
      red[rbuf][w][q * 4 + r][16 + b_lane] = s1[r];
    }
    __syncthreads();  // the ONLY barrier per step (red ping-pong covers reuse)

    // ---- epilogue: every thread handles (be, je2) and (be, je2+1) ----
    float z0 = red[rbuf][0][be][je2] + red[rbuf][1][be][je2] +
               red[rbuf][2][be][je2] + red[rbuf][3][be][je2] + xv0;
    float z1 = red[rbuf][0][be][je2 + 1] + red[rbuf][1][be][je2 + 1] +
               red[rbuf][2][be][je2 + 1] + red[rbuf][3][be][je2 + 1] + xv1;
    float hv0 = tanhf(z0);
    float hv1 = tanhf(z1);
    unsigned int h0h = f2bf(hv0), h1h = f2bf(hv1);
    unsigned int l0 = ((unsigned int)f2bf(hv0 - bf2f((unsigned short)h0h)) & ~1u) | wtag;
    unsigned int l1 = ((unsigned int)f2bf(hv1 - bf2f((unsigned short)h1h)) & ~1u) | wtag;
    unsigned long long val =
        (unsigned long long)(h0h | (h1h << 16)) |
        ((unsigned long long)(l0 | (l1 << 16)) << 32);
    unsigned long long* dst =
        hx + ((size_t)(g * 2 + wbuf) * 16 + be) * 512 + ((jcol0 + je2) >> 1);
    __hip_atomic_store(dst, val, __ATOMIC_RELAXED, __HIP_MEMORY_SCOPE_AGENT);
    if (t == NS) {
      h_last[(size_t)brow * 1024 + jcol0 + je2] = hv0;
      h_last[(size_t)brow * 1024 + jcol0 + je2 + 1] = hv1;
    }
  }
}

// ---------------------------------------------------------------------------
// stage 3: y[b][j] = h_last[b][:] . W_out[:][j] + b_out[j]   (fp32 vector)
// ---------------------------------------------------------------------------
__global__ __launch_bounds__(256, 2) void rnn_out(const float* __restrict__ h_last,
                                                  const float* __restrict__ W_out,
                                                  const float* __restrict__ b_out,
                                                  float* __restrict__ out) {
  __shared__ float smem[16384];
  int tid = threadIdx.x;
  int jl = tid & 127;
  int kh = tid >> 7;
  int j = blockIdx.x * 128 + jl;

  float acc[64];
#pragma unroll
  for (int b = 0; b < 64; ++b) acc[b] = 0.f;

  for (int kc = 0; kc < 4; ++kc) {
    __syncthreads();
    for (int v = tid; v < 16384; v += 256) {
      int kh2 = v >> 13;
      int b = (v >> 7) & 63;
      int kk = v & 127;
      smem[v] = h_last[(size_t)b * 1024 + kh2 * 512 + kc * 128 + kk];
    }
    __syncthreads();
    int kbase = kh * 512 + kc * 128;
    for (int kkc = 0; kkc < 16; ++kkc) {
      float wreg[8];
#pragma unroll
      for (int i = 0; i < 8; ++i)
        wreg[i] = W_out[(size_t)(kbase + kkc * 8 + i) * D_OUT + j];
#pragma unroll
      for (int b = 0; b < 64; ++b) {
        const float* hp = &smem[kh * 8192 + b * 128 + kkc * 8];
#pragma unroll
        for (int i = 0; i < 8; ++i) acc[b] += hp[i] * wreg[i];
      }
    }
  }
  __syncthreads();
  if (kh == 1) {
#pragma unroll
    for (int b = 0; b < 64; ++b) smem[jl * 65 + b] = acc[b];
  }
  __syncthreads();
  if (kh == 0) {
    float bo = b_out[j];
#pragma unroll
    for (int b = 0; b < 64; ++b)
      out[(size_t)b * D_OUT + j] = acc[b] + smem[jl * 65 + b] + bo;
  }
}

// ---------------------------------------------------------------------------
extern "C" void kernel_launch(void* const* d_in, const int* in_sizes, int n_in,
                              void* d_out, int out_size, void* d_ws, size_t ws_size,
                              hipStream_t stream) {
  const int* tokens = (const int*)d_in[0];
  const float* h0 = (const float*)d_in[1];
  const float* embed = (const float*)d_in[2];
  const float* W_ih = (const float*)d_in[3];
  const float* W_hh = (const float*)d_in[4];
  const float* bias_hh = (const float*)d_in[5];
  const float* W_out = (const float*)d_in[6];
  const float* b_out = (const float*)d_in[7];
  float* out = (float*)d_out;

  char* ws = (char*)d_ws;
  // workspace layout (bytes)
  float* xw = (float*)(ws);                                    // 134217728
  unsigned short* wih_hi = (unsigned short*)(ws + 134217728);  // 1048576
  unsigned short* wih_lo = (unsigned short*)(ws + 135266304);  // 1048576
  unsigned long long* hx = (unsigned long long*)(ws + 136314880);  // 524288
  float* h_last = (float*)(ws + 136839168);                    // 262144
  // total: 137101312 bytes

  rnn_init<<<128, 256, 0, stream>>>(h0, hx);
  rnn_pack_wih<<<2048, 256, 0, stream>>>(W_ih, wih_hi, wih_lo);
  rnn_stage1<<<8192, 256, 0, stream>>>(tokens, embed, wih_hi, wih_lo, bias_hh, xw);
  rnn_recur<<<128, 256, 0, stream>>>(xw, W_hh, hx, h_last);
  rnn_out<<<250, 256, 0, stream>>>(h_last, W_out, b_out, out);
}